// Round 1
// baseline (2728.015 us; speedup 1.0000x reference)
//
#include <hip/hip_runtime.h>

#define NGRAPH 1000
#define P      100
#define EPG    1200
#define INF    16
#define HID    64
#define NOUT   5
#define NPW    25   // nodes per wave = P / 4 waves

// LDS layout (61.3 KiB total):
//   A     : P*HID floats (25.6 KB) — X0 of current layer / layer output H
//   Bb    : P*HID floats (25.6 KB) — X1
//   T     : P*16  floats ( 6.4 KB) — X2 scatter temp (16-col blocks) / pool scratch
//   sdinv : P floats
//   sedge : EPG ints — packed local (src | dst<<16)

template <int F>
__device__ __forceinline__ void cheb_layer(
    float* __restrict__ A, float* __restrict__ Bb, float* __restrict__ T,
    const float* __restrict__ sdinv, const int* __restrict__ sedge,
    const float* __restrict__ W, const float* __restrict__ bias,
    int tid, int lane, int w)
{
    // ---------- X1 = -(D^-1/2 A D^-1/2) X0 ----------
    for (int i = tid; i < P * F; i += 256) Bb[i] = 0.0f;
    __syncthreads();
    if (F == 64) {
        for (int e = w; e < EPG; e += 4) {
            int sd = sedge[e];
            int s = sd & 0xFFFF, d = sd >> 16;
            atomicAdd(&Bb[d * 64 + lane], A[s * 64 + lane] * sdinv[s]);
        }
    } else {
        int f = lane & 15, esub = lane >> 4;
        for (int e0 = w * 4; e0 < EPG; e0 += 16) {
            int sd = sedge[e0 + esub];
            int s = sd & 0xFFFF, d = sd >> 16;
            atomicAdd(&Bb[d * 16 + f], A[s * 16 + f] * sdinv[s]);
        }
    }
    __syncthreads();
    for (int i = tid; i < P * F; i += 256) {
        int n = i / F;                       // F is 16 or 64 -> shift
        Bb[i] = -Bb[i] * sdinv[n];
    }
    __syncthreads();

    // ---------- matmul: H = [X0 | X1 | X2] @ W + b, relu ----------
    // lane = output column, wave owns nodes [w*NPW, w*NPW+NPW)
    float acc[NPW];
    float bl = bias[lane];
#pragma unroll
    for (int i = 0; i < NPW; i++) acc[i] = bl;

    // X0 part (W rows [0, F))
    for (int f4 = 0; f4 < F; f4 += 4) {
        float w0 = W[(f4 + 0) * HID + lane];
        float w1 = W[(f4 + 1) * HID + lane];
        float w2 = W[(f4 + 2) * HID + lane];
        float w3 = W[(f4 + 3) * HID + lane];
#pragma unroll
        for (int i = 0; i < NPW; i++) {
            int n = w * NPW + i;
            const float4 xv = *(const float4*)&A[n * F + f4];
            acc[i] += xv.x * w0 + xv.y * w1 + xv.z * w2 + xv.w * w3;
        }
    }
    // X1 part (W rows [F, 2F))
    for (int f4 = 0; f4 < F; f4 += 4) {
        float w0 = W[(F + f4 + 0) * HID + lane];
        float w1 = W[(F + f4 + 1) * HID + lane];
        float w2 = W[(F + f4 + 2) * HID + lane];
        float w3 = W[(F + f4 + 3) * HID + lane];
#pragma unroll
        for (int i = 0; i < NPW; i++) {
            int n = w * NPW + i;
            const float4 xv = *(const float4*)&Bb[n * F + f4];
            acc[i] += xv.x * w0 + xv.y * w1 + xv.z * w2 + xv.w * w3;
        }
    }
    // X2 part, fused by 16-column blocks: X2 = -2 * dinv * segsum(X1*dinv) - X0
    for (int cb = 0; cb < F; cb += 16) {
        for (int i = tid; i < P * 16; i += 256) T[i] = 0.0f;
        __syncthreads();
        {
            int f = lane & 15, esub = lane >> 4;
            for (int e0 = w * 4; e0 < EPG; e0 += 16) {
                int sd = sedge[e0 + esub];
                int s = sd & 0xFFFF, d = sd >> 16;
                atomicAdd(&T[d * 16 + f], Bb[s * F + cb + f] * sdinv[s]);
            }
        }
        __syncthreads();
        for (int f4 = 0; f4 < 16; f4 += 4) {
            float w0 = W[(2 * F + cb + f4 + 0) * HID + lane];
            float w1 = W[(2 * F + cb + f4 + 1) * HID + lane];
            float w2 = W[(2 * F + cb + f4 + 2) * HID + lane];
            float w3 = W[(2 * F + cb + f4 + 3) * HID + lane];
#pragma unroll
            for (int i = 0; i < NPW; i++) {
                int n = w * NPW + i;
                float dn = -2.0f * sdinv[n];
                const float4 tv = *(const float4*)&T[n * 16 + f4];
                const float4 xv = *(const float4*)&A[n * F + cb + f4];
                acc[i] += (tv.x * dn - xv.x) * w0 + (tv.y * dn - xv.y) * w1 +
                          (tv.z * dn - xv.z) * w2 + (tv.w * dn - xv.w) * w3;
            }
        }
        __syncthreads();   // all reads of T (and, on last iter, A/Bb) done
    }
    // write H = relu(acc) into A (P x HID)
#pragma unroll
    for (int i = 0; i < NPW; i++) {
        int n = w * NPW + i;
        A[n * HID + lane] = fmaxf(acc[i], 0.0f);
    }
    __syncthreads();
}

__global__ __launch_bounds__(256) void gnn_kernel(
    const float* __restrict__ feat,
    const int* __restrict__ src, const int* __restrict__ dst,
    const float* __restrict__ W1, const float* __restrict__ b1,
    const float* __restrict__ W2, const float* __restrict__ b2,
    const float* __restrict__ W3, const float* __restrict__ b3,
    const float* __restrict__ Wfc, const float* __restrict__ bfc,
    float* __restrict__ out)
{
    __shared__ __align__(16) float A[P * HID];
    __shared__ __align__(16) float Bb[P * HID];
    __shared__ __align__(16) float T[P * 16];
    __shared__ float sdinv[P];
    __shared__ int   sedge[EPG];

    const int g    = blockIdx.x;
    const int tid  = threadIdx.x;
    const int lane = tid & 63;
    const int w    = tid >> 6;
    const int base = g * P;

    // ---- pack edges to LDS + degree ----
    const int* srcg = src + g * EPG;
    const int* dstg = dst + g * EPG;
    for (int i = tid; i < P; i += 256) sdinv[i] = 0.0f;
    __syncthreads();
    for (int e = tid; e < EPG; e += 256) {
        int s = srcg[e] - base;
        int d = dstg[e] - base;
        sedge[e] = s | (d << 16);
        atomicAdd(&sdinv[d], 1.0f);
    }
    __syncthreads();
    for (int i = tid; i < P; i += 256) {
        float dg = fmaxf(sdinv[i], 1.0f);
        sdinv[i] = 1.0f / sqrtf(dg);
    }
    // ---- load feat (P x INF) into A ----
    const float* fg = feat + (size_t)base * INF;
    for (int i = tid; i < P * INF; i += 256) A[i] = fg[i];
    __syncthreads();

    cheb_layer<INF>(A, Bb, T, sdinv, sedge, W1, b1, tid, lane, w);
    cheb_layer<HID>(A, Bb, T, sdinv, sedge, W2, b2, tid, lane, w);
    cheb_layer<HID>(A, Bb, T, sdinv, sedge, W3, b3, tid, lane, w);

    // ---- mean pool over nodes + FC ----
    float s = 0.0f;
    for (int n = w; n < P; n += 4) s += A[n * HID + lane];
    T[w * 64 + lane] = s;
    __syncthreads();
    if (tid < HID) {
        float hg = (T[tid] + T[64 + tid] + T[128 + tid] + T[192 + tid]) * (1.0f / P);
        T[256 + tid] = hg;
    }
    __syncthreads();
    if (tid < NOUT) {
        float o = bfc[tid];
        for (int c = 0; c < HID; c++) o += T[256 + c] * Wfc[c * NOUT + tid];
        out[g * NOUT + tid] = o;
    }
}

extern "C" void kernel_launch(void* const* d_in, const int* in_sizes, int n_in,
                              void* d_out, int out_size, void* d_ws, size_t ws_size,
                              hipStream_t stream)
{
    const float* feat = (const float*)d_in[0];
    const int*   src  = (const int*)d_in[1];
    const int*   dst  = (const int*)d_in[2];
    // d_in[3] graph_ids, d_in[4] n_graphs: implied by fixed layout (P nodes/graph)
    const float* W1  = (const float*)d_in[5];
    const float* b1  = (const float*)d_in[6];
    const float* W2  = (const float*)d_in[7];
    const float* b2  = (const float*)d_in[8];
    const float* W3  = (const float*)d_in[9];
    const float* b3  = (const float*)d_in[10];
    const float* Wfc = (const float*)d_in[11];
    const float* bfc = (const float*)d_in[12];
    float* out = (float*)d_out;

    gnn_kernel<<<NGRAPH, 256, 0, stream>>>(feat, src, dst,
                                           W1, b1, W2, b2, W3, b3, Wfc, bfc, out);
}

// Round 4
// 307.790 us; speedup vs baseline: 8.8632x; 8.8632x over previous
//
#include <hip/hip_runtime.h>

#define NGRAPH 1000
#define P      100
#define EPG    1200
#define INF    16
#define HID    64
#define NOUT   5

#define ASTR   68    // A row stride in floats (16B-aligned rows, non-pow2 bank spread)
#define TSTR   20    // T1/T2 row stride in floats
#define NPAD   104   // padded node rows: 8 groups * 13

// LDS: A 28288 + T1 8320 + T2 8320 + csr_src 2400 + csr_off 404 + cur 400
//      + sdinv 400 + deg 400 = 48,932 B  -> 3 blocks/CU (limit 54,613)

// Gather one 16-column slice D[n][0..16) for all n from CSR.
// isX2=0: D = -dinv[n] * sum_e dinv[s]*S[s]            (X1 = -Ax(X0))
// isX2=1: D = -2*dinv[n]*sum_e dinv[s]*S[s] - A0[n]    (X2 = -2Ax(X1) - X0)
__device__ __forceinline__ void prop16(
    const float* __restrict__ S, int sstride, int soff,
    float* __restrict__ D,
    const float* __restrict__ A0, int aoff, int isX2,
    const unsigned short* __restrict__ csr_src,
    const int* __restrict__ csr_off,
    const float* __restrict__ sdinv,
    int tid)
{
    const int q = tid & 3;        // feature quad: features q*4..q*4+3
    const int slot = tid >> 2;    // 64 node slots
    for (int pass = 0; pass < 2; pass++) {
        int n = slot + (pass << 6);
        if (n < P) {
            int kb = csr_off[n], ke = csr_off[n + 1];
            float ax = 0.f, ay = 0.f, az = 0.f, aw = 0.f;
            for (int k = kb; k < ke; k++) {
                int s = csr_src[k];
                float ws = sdinv[s];
                const float4 x = *(const float4*)&S[s * sstride + soff + q * 4];
                ax += ws * x.x; ay += ws * x.y; az += ws * x.z; aw += ws * x.w;
            }
            float dn = sdinv[n];
            float4 o;
            if (!isX2) {
                float m = -dn;
                o.x = m * ax; o.y = m * ay; o.z = m * az; o.w = m * aw;
            } else {
                float m = -2.f * dn;
                const float4 x0 = *(const float4*)&A0[n * ASTR + aoff + q * 4];
                o.x = m * ax - x0.x; o.y = m * ay - x0.y;
                o.z = m * az - x0.z; o.w = m * aw - x0.w;
            }
            *(float4*)&D[n * TSTR + q * 4] = o;
        }
    }
}

// One ChebConv(K=3) layer: A (stride ASTR, F cols) -> relu([X0|X1|X2]@W + b) into A
template <int F>
__device__ __forceinline__ void cheb_layer(
    float* __restrict__ A, float* __restrict__ T1, float* __restrict__ T2,
    const unsigned short* __restrict__ csr_src,
    const int* __restrict__ csr_off,
    const float* __restrict__ sdinv,
    const float* __restrict__ W, const float* __restrict__ bias,
    int tid)
{
    const int lane = tid & 63;
    const int colg = lane & 31;                     // owns cols colg, colg+32
    const int g2 = ((tid >> 6) << 1) | (lane >> 5); // node group 0..7
    const int n0 = g2 * 13;                         // nodes n0..n0+12 (padded to 104)

    float acc0[13], acc1[13];
    const float b0 = bias[colg], b1v = bias[colg + 32];
#pragma unroll
    for (int i = 0; i < 13; i++) { acc0[i] = b0; acc1[i] = b1v; }

    for (int cb = 0; cb < F; cb += 16) {
        prop16(A, ASTR, cb, T1, (const float*)0, 0, 0, csr_src, csr_off, sdinv, tid);
        __syncthreads();
        prop16(T1, TSTR, 0, T2, A, cb, 1, csr_src, csr_off, sdinv, tid);
        __syncthreads();

        // partial matmul over this 16-feature slice, 3 sections (X0, X1, X2)
        for (int sec = 0; sec < 3; sec++) {
            const float* xp; int xstr, xoff, wrow0;
            if (sec == 0)      { xp = A;  xstr = ASTR; xoff = cb; wrow0 = cb; }
            else if (sec == 1) { xp = T1; xstr = TSTR; xoff = 0;  wrow0 = F + cb; }
            else               { xp = T2; xstr = TSTR; xoff = 0;  wrow0 = 2 * F + cb; }
            for (int j4 = 0; j4 < 16; j4 += 4) {
                const float* wp = &W[(wrow0 + j4) * HID + colg];
                const float w00 = wp[0],   w01 = wp[32];
                const float w10 = wp[64],  w11 = wp[96];
                const float w20 = wp[128], w21 = wp[160];
                const float w30 = wp[192], w31 = wp[224];
                const float* xb = xp + n0 * xstr + xoff + j4;
#pragma unroll
                for (int i = 0; i < 13; i++) {
                    const float4 x = *(const float4*)&xb[i * xstr];
                    acc0[i] += x.x * w00 + x.y * w10 + x.z * w20 + x.w * w30;
                    acc1[i] += x.x * w01 + x.y * w11 + x.z * w21 + x.w * w31;
                }
            }
        }
        __syncthreads();   // T1/T2 reads done before next slice's gather overwrites
    }

    // H = relu(acc) -> A   (padded rows 100..103 stay zero: write is guarded)
#pragma unroll
    for (int i = 0; i < 13; i++) {
        int n = n0 + i;
        if (n < P) {
            A[n * ASTR + colg]      = fmaxf(acc0[i], 0.f);
            A[n * ASTR + colg + 32] = fmaxf(acc1[i], 0.f);
        }
    }
    __syncthreads();
}

__global__ __launch_bounds__(256, 3) void gnn_kernel(
    const float* __restrict__ feat,
    const int* __restrict__ src, const int* __restrict__ dst,
    const float* __restrict__ W1, const float* __restrict__ b1,
    const float* __restrict__ W2, const float* __restrict__ b2,
    const float* __restrict__ W3, const float* __restrict__ b3,
    const float* __restrict__ Wfc, const float* __restrict__ bfc,
    float* __restrict__ out)
{
    __shared__ __align__(16) float A[NPAD * ASTR];
    __shared__ __align__(16) float T1[NPAD * TSTR];
    __shared__ __align__(16) float T2[NPAD * TSTR];
    __shared__ unsigned short csr_src[EPG];
    __shared__ int   csr_off[P + 1];
    __shared__ int   cur[P];
    __shared__ float sdinv[P];
    __shared__ int   deg[P];

    const int g = blockIdx.x;
    const int tid = threadIdx.x;
    const int base = g * P;
    const int* srcg = src + g * EPG;
    const int* dstg = dst + g * EPG;

    // ---- init: degree=0, zero padded rows of A/T1/T2 ----
    for (int i = tid; i < P; i += 256) deg[i] = 0;
    for (int i = tid; i < 4 * ASTR; i += 256) A[P * ASTR + i - (P & 0) * 0 + 0] = 0.f; // rows 100..103 of A start at 100*ASTR... (see below)
    __syncthreads();
    // (re-do padded-row zeroing with explicit indexing, overwriting the above)
    for (int i = tid; i < (NPAD - P) * ASTR; i += 256) A[P * ASTR + i] = 0.f;
    for (int i = tid; i < (NPAD - P) * TSTR; i += 256) { T1[P * TSTR + i] = 0.f; T2[P * TSTR + i] = 0.f; }
    __syncthreads();

    // ---- degree count + feat load ----
    for (int e = tid; e < EPG; e += 256) {
        int d = dstg[e] - base;
        atomicAdd(&deg[d], 1);
    }
    for (int i = tid; i < P * INF; i += 256) {
        int n = i >> 4, f = i & 15;
        A[n * ASTR + f] = feat[(size_t)base * INF + i];
    }
    __syncthreads();

    for (int i = tid; i < P; i += 256) {
        int dg = deg[i] > 1 ? deg[i] : 1;
        sdinv[i] = rsqrtf((float)dg);
    }
    // ---- prefix scan of degrees: simple serial by thread 0 ----
    if (tid == 0) {
        int run = 0;
        csr_off[0] = 0;
        for (int i = 0; i < P; i++) { run += deg[i]; csr_off[i + 1] = run; }
    }
    __syncthreads();
    for (int i = tid; i < P; i += 256) cur[i] = csr_off[i];
    __syncthreads();
    // ---- CSR fill (re-read edges from global; L2-resident) ----
    for (int e = tid; e < EPG; e += 256) {
        int s = srcg[e] - base;
        int d = dstg[e] - base;
        int pos = atomicAdd(&cur[d], 1);
        csr_src[pos] = (unsigned short)s;
    }
    __syncthreads();

    // ---- 3 ChebConv layers ----
    cheb_layer<INF>(A, T1, T2, csr_src, csr_off, sdinv, W1, b1, tid);
    cheb_layer<HID>(A, T1, T2, csr_src, csr_off, sdinv, W2, b2, tid);
    cheb_layer<HID>(A, T1, T2, csr_src, csr_off, sdinv, W3, b3, tid);

    // ---- mean pool + FC ----
    {
        const int lane = tid & 63, w = tid >> 6;
        float s = 0.f;
        for (int n = w; n < P; n += 4) s += A[n * ASTR + lane];
        T1[w * 64 + lane] = s;
    }
    __syncthreads();
    if (tid < HID) {
        float hg = (T1[tid] + T1[64 + tid] + T1[128 + tid] + T1[192 + tid]) * (1.0f / P);
        T1[256 + tid] = hg;
    }
    __syncthreads();
    if (tid < NOUT) {
        float o = bfc[tid];
        for (int c = 0; c < HID; c++) o += T1[256 + c] * Wfc[c * NOUT + tid];
        out[g * NOUT + tid] = o;
    }
}

extern "C" void kernel_launch(void* const* d_in, const int* in_sizes, int n_in,
                              void* d_out, int out_size, void* d_ws, size_t ws_size,
                              hipStream_t stream)
{
    const float* feat = (const float*)d_in[0];
    const int*   src  = (const int*)d_in[1];
    const int*   dst  = (const int*)d_in[2];
    const float* W1  = (const float*)d_in[5];
    const float* b1  = (const float*)d_in[6];
    const float* W2  = (const float*)d_in[7];
    const float* b2  = (const float*)d_in[8];
    const float* W3  = (const float*)d_in[9];
    const float* b3  = (const float*)d_in[10];
    const float* Wfc = (const float*)d_in[11];
    const float* bfc = (const float*)d_in[12];
    float* out = (float*)d_out;

    gnn_kernel<<<NGRAPH, 256, 0, stream>>>(feat, src, dst,
                                           W1, b1, W2, b2, W3, b3, Wfc, bfc, out);
}

// Round 5
// 299.057 us; speedup vs baseline: 9.1221x; 1.0292x over previous
//
#include <hip/hip_runtime.h>

#define NGRAPH 1000
#define P      100
#define EPG    1200
#define INF    16
#define HID    64
#define NOUT   5

#define ASTR   68    // A row stride in floats (17 granules: odd -> bank spread)
#define TSTR   20    // T1/T2 row stride in floats (5 granules: odd)
#define NPAD   112   // padded node rows: 16 groups * 7

// LDS: A 112*68*4=30464 + T1/T2 2*112*20*4=17920 + csr_src 2400 + csr_off 404
//      + cur 400 + sdinv 400 + deg 400 = 52,388 B -> 3 blocks/CU (3x52.4KB<160KB)

__device__ __forceinline__ void fma4(float4& a, float s, const float4 w) {
    a.x += s * w.x; a.y += s * w.y; a.z += s * w.z; a.w += s * w.w;
}

// Gather one 16-column slice D[n][0..16) for all n from CSR.
// isX2=0: D = -dinv[n] * sum_e dinv[s]*S[s]            (X1 = -Ax(X0))
// isX2=1: D = -2*dinv[n]*sum_e dinv[s]*S[s] - A0[n]    (X2 = -2Ax(X1) - X0)
__device__ __forceinline__ void prop16(
    const float* __restrict__ S, int sstride, int soff,
    float* __restrict__ D,
    const float* __restrict__ A0, int aoff, int isX2,
    const unsigned short* __restrict__ csr_src,
    const int* __restrict__ csr_off,
    const float* __restrict__ sdinv,
    int tid)
{
    const int q = tid & 3;        // feature quad: features q*4..q*4+3
    const int slot = tid >> 2;    // 64 node slots
    for (int pass = 0; pass < 2; pass++) {
        int n = slot + (pass << 6);
        if (n < P) {
            int kb = csr_off[n], ke = csr_off[n + 1];
            float ax = 0.f, ay = 0.f, az = 0.f, aw = 0.f;
            for (int k = kb; k < ke; k++) {
                int s = csr_src[k];
                float ws = sdinv[s];
                const float4 x = *(const float4*)&S[s * sstride + soff + q * 4];
                ax += ws * x.x; ay += ws * x.y; az += ws * x.z; aw += ws * x.w;
            }
            float dn = sdinv[n];
            float4 o;
            if (!isX2) {
                float m = -dn;
                o.x = m * ax; o.y = m * ay; o.z = m * az; o.w = m * aw;
            } else {
                float m = -2.f * dn;
                const float4 x0 = *(const float4*)&A0[n * ASTR + aoff + q * 4];
                o.x = m * ax - x0.x; o.y = m * ay - x0.y;
                o.z = m * az - x0.z; o.w = m * aw - x0.w;
            }
            *(float4*)&D[n * TSTR + q * 4] = o;
        }
    }
}

// One ChebConv(K=3) layer: A (stride ASTR, F cols) -> relu([X0|X1|X2]@W + b) into A
// Matmul tiling: thread = (cq = tid&15 -> cols cq*4..cq*4+3, ng = tid>>4 -> nodes ng*7..+6)
// x-read: one ds_read_b128 serves 16 FMA; 4 unique chunks per wave (conflict-free).
template <int F>
__device__ __forceinline__ void cheb_layer(
    float* __restrict__ A, float* __restrict__ T1, float* __restrict__ T2,
    const unsigned short* __restrict__ csr_src,
    const int* __restrict__ csr_off,
    const float* __restrict__ sdinv,
    const float* __restrict__ W, const float* __restrict__ bias,
    int tid)
{
    const int cq4 = (tid & 15) * 4;   // first of 4 contiguous output cols
    const int ng  = tid >> 4;         // node group 0..15
    const int n0  = ng * 7;           // nodes n0..n0+6 (padded to 112)

    float4 acc[7];
    const float4 bv = *(const float4*)&bias[cq4];
#pragma unroll
    for (int i = 0; i < 7; i++) acc[i] = bv;

    for (int cb = 0; cb < F; cb += 16) {
        prop16(A, ASTR, cb, T1, (const float*)0, 0, 0, csr_src, csr_off, sdinv, tid);
        __syncthreads();
        prop16(T1, TSTR, 0, T2, A, cb, 1, csr_src, csr_off, sdinv, tid);
        __syncthreads();

        // partial matmul over this 16-feature slice, 3 sections (X0, X1, X2)
        for (int sec = 0; sec < 3; sec++) {
            const float* xp; int xstr, xoff, wrow0;
            if (sec == 0)      { xp = A;  xstr = ASTR; xoff = cb; wrow0 = cb; }
            else if (sec == 1) { xp = T1; xstr = TSTR; xoff = 0;  wrow0 = F + cb; }
            else               { xp = T2; xstr = TSTR; xoff = 0;  wrow0 = 2 * F + cb; }
            for (int j4 = 0; j4 < 16; j4 += 4) {
                const float4 w0 = *(const float4*)&W[(wrow0 + j4 + 0) * HID + cq4];
                const float4 w1 = *(const float4*)&W[(wrow0 + j4 + 1) * HID + cq4];
                const float4 w2 = *(const float4*)&W[(wrow0 + j4 + 2) * HID + cq4];
                const float4 w3 = *(const float4*)&W[(wrow0 + j4 + 3) * HID + cq4];
                const float* xb = xp + n0 * xstr + xoff + j4;
#pragma unroll
                for (int i = 0; i < 7; i++) {
                    const float4 x = *(const float4*)&xb[i * xstr];
                    fma4(acc[i], x.x, w0); fma4(acc[i], x.y, w1);
                    fma4(acc[i], x.z, w2); fma4(acc[i], x.w, w3);
                }
            }
        }
        __syncthreads();   // T1/T2 reads done before next slice's gather overwrites
    }

    // H = relu(acc) -> A   (padded rows 100..111 stay zero: write is guarded)
#pragma unroll
    for (int i = 0; i < 7; i++) {
        int n = n0 + i;
        if (n < P) {
            float4 o;
            o.x = fmaxf(acc[i].x, 0.f); o.y = fmaxf(acc[i].y, 0.f);
            o.z = fmaxf(acc[i].z, 0.f); o.w = fmaxf(acc[i].w, 0.f);
            *(float4*)&A[n * ASTR + cq4] = o;
        }
    }
    __syncthreads();
}

__global__ __launch_bounds__(256, 3) void gnn_kernel(
    const float* __restrict__ feat,
    const int* __restrict__ src, const int* __restrict__ dst,
    const float* __restrict__ W1, const float* __restrict__ b1,
    const float* __restrict__ W2, const float* __restrict__ b2,
    const float* __restrict__ W3, const float* __restrict__ b3,
    const float* __restrict__ Wfc, const float* __restrict__ bfc,
    float* __restrict__ out)
{
    __shared__ __align__(16) float A[NPAD * ASTR];
    __shared__ __align__(16) float T1[NPAD * TSTR];
    __shared__ __align__(16) float T2[NPAD * TSTR];
    __shared__ unsigned short csr_src[EPG];
    __shared__ int   csr_off[P + 1];
    __shared__ int   cur[P];
    __shared__ float sdinv[P];
    __shared__ int   deg[P];

    const int g = blockIdx.x;
    const int tid = threadIdx.x;
    const int base = g * P;
    const int* srcg = src + g * EPG;
    const int* dstg = dst + g * EPG;

    // ---- init: degree=0, zero padded rows of A/T1/T2 ----
    for (int i = tid; i < P; i += 256) deg[i] = 0;
    for (int i = tid; i < (NPAD - P) * ASTR; i += 256) A[P * ASTR + i] = 0.f;
    for (int i = tid; i < (NPAD - P) * TSTR; i += 256) { T1[P * TSTR + i] = 0.f; T2[P * TSTR + i] = 0.f; }
    __syncthreads();

    // ---- degree count + feat load ----
    for (int e = tid; e < EPG; e += 256) {
        int d = dstg[e] - base;
        atomicAdd(&deg[d], 1);
    }
    for (int i = tid; i < P * INF; i += 256) {
        int n = i >> 4, f = i & 15;
        A[n * ASTR + f] = feat[(size_t)base * INF + i];
    }
    __syncthreads();

    for (int i = tid; i < P; i += 256) {
        int dg = deg[i] > 1 ? deg[i] : 1;
        sdinv[i] = rsqrtf((float)dg);
    }
    // ---- prefix scan of degrees: serial by thread 0 (P=100, negligible) ----
    if (tid == 0) {
        int run = 0;
        csr_off[0] = 0;
        for (int i = 0; i < P; i++) { run += deg[i]; csr_off[i + 1] = run; }
    }
    __syncthreads();
    for (int i = tid; i < P; i += 256) cur[i] = csr_off[i];
    __syncthreads();
    // ---- CSR fill (re-read edges from global; L2-resident) ----
    for (int e = tid; e < EPG; e += 256) {
        int s = srcg[e] - base;
        int d = dstg[e] - base;
        int pos = atomicAdd(&cur[d], 1);
        csr_src[pos] = (unsigned short)s;
    }
    __syncthreads();

    // ---- 3 ChebConv layers ----
    cheb_layer<INF>(A, T1, T2, csr_src, csr_off, sdinv, W1, b1, tid);
    cheb_layer<HID>(A, T1, T2, csr_src, csr_off, sdinv, W2, b2, tid);
    cheb_layer<HID>(A, T1, T2, csr_src, csr_off, sdinv, W3, b3, tid);

    // ---- mean pool + FC ----
    {
        const int lane = tid & 63, w = tid >> 6;
        float s = 0.f;
        for (int n = w; n < P; n += 4) s += A[n * ASTR + lane];
        T1[w * 64 + lane] = s;
    }
    __syncthreads();
    if (tid < HID) {
        float hg = (T1[tid] + T1[64 + tid] + T1[128 + tid] + T1[192 + tid]) * (1.0f / P);
        T1[256 + tid] = hg;
    }
    __syncthreads();
    if (tid < NOUT) {
        float o = bfc[tid];
        for (int c = 0; c < HID; c++) o += T1[256 + c] * Wfc[c * NOUT + tid];
        out[g * NOUT + tid] = o;
    }
}

extern "C" void kernel_launch(void* const* d_in, const int* in_sizes, int n_in,
                              void* d_out, int out_size, void* d_ws, size_t ws_size,
                              hipStream_t stream)
{
    const float* feat = (const float*)d_in[0];
    const int*   src  = (const int*)d_in[1];
    const int*   dst  = (const int*)d_in[2];
    const float* W1  = (const float*)d_in[5];
    const float* b1  = (const float*)d_in[6];
    const float* W2  = (const float*)d_in[7];
    const float* b2  = (const float*)d_in[8];
    const float* W3  = (const float*)d_in[9];
    const float* b3  = (const float*)d_in[10];
    const float* Wfc = (const float*)d_in[11];
    const float* bfc = (const float*)d_in[12];
    float* out = (float*)d_out;

    gnn_kernel<<<NGRAPH, 256, 0, stream>>>(feat, src, dst,
                                           W1, b1, W2, b2, W3, b3, Wfc, bfc, out);
}